// Round 4
// baseline (145.808 us; speedup 1.0000x reference)
//
#include <hip/hip_runtime.h>
#include <hip/hip_bf16.h>
#include <hip/hip_fp16.h>

#define B_ 128
#define S_ 200
#define QN_ 20000
#define V_ 128
#define K_ 128
#define C_ 64
#define SUM_ 128
#define NCH 4           // scan chunks (S = 4 * 50)
#define CL 50           // steps per chunk
#define RP 52           // padded row count in LDS

using short8 = __attribute__((ext_vector_type(8))) short;
using f32x4  = __attribute__((ext_vector_type(4))) float;

__device__ __forceinline__ float fast_sigmoid(float x) { return 1.f / (1.f + __expf(-x)); }
__device__ __forceinline__ float fast_tanh(float x)    { return 1.f - 2.f / (__expf(2.f * x) + 1.f); }

template<bool BF>
__device__ __forceinline__ float ld(const void* p, long long i) {
    if (BF) return __bfloat162float(((const __hip_bfloat16*)p)[i]);
    return ((const float*)p)[i];
}

__device__ __forceinline__ unsigned short f2bf(float v) {
    __hip_bfloat16 h = __float2bfloat16(v);
    unsigned short u;
    __builtin_memcpy(&u, &h, 2);
    return u;
}

__device__ __forceinline__ void ld4h(const __half* p, float* out) {
    const float2 f01 = __half22float2(*(const __half2*)p);
    const float2 f23 = __half22float2(*(const __half2*)(p + 2));
    out[0] = f01.x; out[1] = f01.y; out[2] = f23.x; out[3] = f23.y;
}

__device__ __forceinline__ int probe_flag_wave(const void* erase_b) {
    const unsigned* w = (const unsigned*)erase_b;
    const int lane = threadIdx.x & 63;
    const unsigned lo = w[lane] & 0xffffu;
    const float f = __uint_as_float(lo << 16);
    const unsigned long long bal = __ballot(!(fabsf(f) <= 0.5f));
    return (__popcll(bal) <= 8) ? 1 : 0;  // 1 = bf16
}

// ===== Prepack (blocks 0..19) + wt softmax (blocks 20..147, one per batch) =====
template<bool BF>
__device__ __forceinline__ void wt_body(
    const void* q_emb, const void* key_memory, const int* __restrict__ target_id,
    int b, float* __restrict__ wt_buf)
{
    const int t = threadIdx.x;
    if (t >= 64) return;
    const long long qrow = (long long)target_id[b] * K_;
    float logit = 0.f;
    #pragma unroll 8
    for (int i = 0; i < K_; ++i)
        logit += ld<BF>(q_emb, qrow + i) * ld<BF>(key_memory, i * C_ + t);
    float m = logit;
    for (int off = 32; off > 0; off >>= 1)
        m = fmaxf(m, __shfl_xor(m, off, 64));
    const float ex = __expf(logit - m);
    float ssum = ex;
    for (int off = 32; off > 0; off >>= 1)
        ssum += __shfl_xor(ssum, off, 64);
    wt_buf[b * C_ + t] = ex / ssum;
}

__global__ __launch_bounds__(256) void dkvmn_prepack(
    const void* erase_W, const void* add_W, const void* key_memory,
    const void* erase_b, const void* q_emb, const int* __restrict__ target_id,
    unsigned short* __restrict__ wpack, float* __restrict__ wt_buf)
{
    const int bf = probe_flag_wave(erase_b);
    if (blockIdx.x >= 20) {
        const int b = blockIdx.x - 20;
        if (bf) wt_body<true>(q_emb, key_memory, target_id, b, wt_buf);
        else    wt_body<false>(q_emb, key_memory, target_id, b, wt_buf);
        return;
    }
    const int fid = blockIdx.x * 256 + threadIdx.x;  // 0..5119
    if (fid >= 5120) return;
    const int lane = fid & 63;
    const int ks = (fid >> 6) & 3;
    const int wv = (fid >> 8) & 3;
    const int q  = fid >> 10;
    const int nt = wv + 4 * q;
    const void* Wsrc;
    int ncol, ldn;
    if (q < 2)      { Wsrc = erase_W;    ncol = nt * 16 + (lane & 15);        ldn = 128; }
    else if (q < 4) { Wsrc = add_W;      ncol = (nt - 8) * 16 + (lane & 15);  ldn = 128; }
    else            { Wsrc = key_memory; ncol = (nt - 16) * 16 + (lane & 15); ldn = 64; }
    const int k8 = (lane >> 4) * 8;
    unsigned short o[8];
    #pragma unroll
    for (int jj = 0; jj < 8; ++jj) {
        const long long idx = (long long)(ks * 32 + k8 + jj) * ldn + ncol;
        const float v = bf ? ld<true>(Wsrc, idx) : ld<false>(Wsrc, idx);
        o[jj] = f2bf(v);
    }
    *(uint4*)(wpack + (size_t)fid * 8) = *(const uint4*)o;
}

// ============ Fused phase1+scan: 512 blocks (b, chunk), 256 threads ============
// NCH=4/CL=50: 512 blocks at 2 blocks/CU (LDS ~69.5 KB) = one dispatch round;
// scan wall-time unchanged vs NCH=8 (same total steps), du halves to 16.8 MB
// -> 2.1 MB per XCD -> L2-resident for foldfinal.
struct FusedLDS {
    unsigned short ivA[RP * 136];
    unsigned short qvA[RP * 136];
    __half esh[RP * 136];
    __half ash[RP * 136];
    float  wlog[RP * 68];
    int sidx[RP], sqid[RP];
};

template<bool BF>
__device__ __forceinline__ void fused_body(
    const void* q_emb, const void* i_emb,
    const void* erase_b, const void* add_b,
    const int* __restrict__ input, const unsigned short* __restrict__ wpack,
    __half2* __restrict__ du, FusedLDS& sm)
{
    const int bid = blockIdx.x;
    const int b = bid & 127;            // XCD affinity: all chunks of b on b%8
    const int chunk = bid >> 7;         // 0..3
    const int t = threadIdx.x;          // 0..255
    const int wv = t >> 6;
    const int lane = t & 63;
    const int lrow = lane & 15;
    const int lk8 = (lane >> 4) * 8;

    if (t < RP) {
        const int s = (t < CL) ? t : 0;
        const int ix = input[b * S_ + chunk * CL + s];
        sm.sidx[t] = ix;
        sm.sqid[t] = ix > QN_ ? ix - QN_ : ix;
    }
    __syncthreads();

    // stage 2 tensors x RP rows x 16 segs of 8 elements = 1664 jobs
    #pragma unroll
    for (int r = 0; r < 7; ++r) {
        const int j = t + 256 * r;      // 0..1791
        if (j < 2 * RP * 16) {
            const int tensor = j >= RP * 16;
            const int jj = j - tensor * (RP * 16);
            const int row = jj >> 4;
            const int seg = jj & 15;
            const int gr = tensor ? sm.sqid[row] : sm.sidx[row];
            unsigned short* dst = (tensor ? sm.qvA : sm.ivA) + row * 136 + seg * 8;
            if (BF) {
                const unsigned short* src = (const unsigned short*)(tensor ? q_emb : i_emb);
                *(uint4*)dst = *(const uint4*)(src + (long long)gr * 128 + seg * 8);
            } else {
                const float* src = (const float*)(tensor ? q_emb : i_emb) + (long long)gr * 128 + seg * 8;
                const float4 f0 = *(const float4*)src;
                const float4 f1 = *(const float4*)(src + 4);
                unsigned short o[8] = {f2bf(f0.x), f2bf(f0.y), f2bf(f0.z), f2bf(f0.w),
                                       f2bf(f1.x), f2bf(f1.y), f2bf(f1.z), f2bf(f1.w)};
                *(uint4*)dst = *(const uint4*)o;
            }
        }
    }

    short8 bfr[5][4];
    int nco[5];
    float biasq[4];
    #pragma unroll
    for (int q = 0; q < 5; ++q) {
        const int nt = wv + 4 * q;
        if (q < 2)      nco[q] = nt * 16 + lrow;
        else if (q < 4) nco[q] = (nt - 8) * 16 + lrow;
        else            nco[q] = (nt - 16) * 16 + lrow;
        if (q < 2)      biasq[q] = ld<BF>(erase_b, nco[q]);
        else if (q < 4) biasq[q] = ld<BF>(add_b, nco[q]);
        #pragma unroll
        for (int ks = 0; ks < 4; ++ks)
            bfr[q][ks] = *(const short8*)(wpack +
                ((size_t)(((q * 4 + wv) * 4 + ks) * 64 + lane)) * 8);
    }
    __syncthreads();

    // e/a: 4 m-tiles cover rows 0..63; stores guarded to rows < CL
    #pragma unroll
    for (int mt = 0; mt < 4; ++mt) {
        short8 afr[4];
        const unsigned short* ar = sm.ivA + (mt * 16 + lrow) * 136 + lk8;
        #pragma unroll
        for (int ks = 0; ks < 4; ++ks)
            afr[ks] = *(const short8*)(ar + ks * 32);
        #pragma unroll
        for (int q = 0; q < 4; ++q) {
            f32x4 acc = {0.f, 0.f, 0.f, 0.f};
            #pragma unroll
            for (int ks = 0; ks < 4; ++ks)
                acc = __builtin_amdgcn_mfma_f32_16x16x32_bf16(afr[ks], bfr[q][ks], acc, 0, 0, 0);
            const int ncol = nco[q];
            const float bb = biasq[q];
            #pragma unroll
            for (int r = 0; r < 4; ++r) {
                const int orow = mt * 16 + (lane >> 4) * 4 + r;
                if (orow < CL) {
                    const float y = acc[r] + bb;
                    if (q < 2) sm.esh[orow * 136 + ncol] = __float2half(fast_sigmoid(y));
                    else       sm.ash[orow * 136 + ncol] = __float2half(fast_tanh(y));
                }
            }
        }
    }
    // w logits
    #pragma unroll
    for (int mt = 0; mt < 4; ++mt) {
        short8 afr[4];
        const unsigned short* ar = sm.qvA + (mt * 16 + lrow) * 136 + lk8;
        #pragma unroll
        for (int ks = 0; ks < 4; ++ks)
            afr[ks] = *(const short8*)(ar + ks * 32);
        f32x4 acc = {0.f, 0.f, 0.f, 0.f};
        #pragma unroll
        for (int ks = 0; ks < 4; ++ks)
            acc = __builtin_amdgcn_mfma_f32_16x16x32_bf16(afr[ks], bfr[4][ks], acc, 0, 0, 0);
        #pragma unroll
        for (int r = 0; r < 4; ++r) {
            const int orow = mt * 16 + (lane >> 4) * 4 + r;
            if (orow < CL)
                sm.wlog[orow * 68 + nco[4]] = acc[r];
        }
    }
    __syncthreads();

    // softmax over c=64 per row; 2 passes of 32 rows; aligned 8-thread groups
    #pragma unroll
    for (int pass = 0; pass < 2; ++pass) {
        const int row = pass * 32 + (t >> 3);
        if (row < CL) {
            const int cs = t & 7;
            float* wr = &sm.wlog[row * 68 + cs * 8];
            float v[8];
            *(float4*)&v[0] = *(const float4*)&wr[0];
            *(float4*)&v[4] = *(const float4*)&wr[4];
            float m = v[0];
            #pragma unroll
            for (int ii = 1; ii < 8; ++ii) m = fmaxf(m, v[ii]);
            m = fmaxf(m, __shfl_xor(m, 1, 64));
            m = fmaxf(m, __shfl_xor(m, 2, 64));
            m = fmaxf(m, __shfl_xor(m, 4, 64));
            float s = 0.f;
            #pragma unroll
            for (int ii = 0; ii < 8; ++ii) { v[ii] = __expf(v[ii] - m); s += v[ii]; }
            s += __shfl_xor(s, 1, 64);
            s += __shfl_xor(s, 2, 64);
            s += __shfl_xor(s, 4, 64);
            const float inv = 1.f / s;
            *(float4*)&wr[0] = make_float4(v[0]*inv, v[1]*inv, v[2]*inv, v[3]*inv);
            *(float4*)&wr[4] = make_float4(v[4]*inv, v[5]*inv, v[6]*inv, v[7]*inv);
        }
    }
    __syncthreads();

    const int vg = t >> 3;
    const int cg = t & 7;
    const int v0 = vg * 4, c0 = cg * 8;

    float ym[4][8], Dm[4][8];
    #pragma unroll
    for (int i = 0; i < 4; ++i)
        #pragma unroll
        for (int j = 0; j < 8; ++j) { ym[i][j] = 0.f; Dm[i][j] = 1.f; }

    for (int s = 0; s < CL; ++s) {
        float ev[4], av[4], wv8[8];
        ld4h(sm.esh + s * 136 + v0, ev);
        ld4h(sm.ash + s * 136 + v0, av);
        *(float4*)&wv8[0] = *(const float4*)(sm.wlog + s * 68 + c0);
        *(float4*)&wv8[4] = *(const float4*)(sm.wlog + s * 68 + c0 + 4);
        #pragma unroll
        for (int i = 0; i < 4; ++i) {
            #pragma unroll
            for (int j = 0; j < 8; ++j) {
                const float d = fmaf(-ev[i], wv8[j], 1.f);
                Dm[i][j] *= d;
                ym[i][j] = fmaf(d, ym[i][j], av[i] * wv8[j]);
            }
        }
    }

    __half2* dbase = du + ((size_t)(chunk * B_ + b) * (V_ * C_));
    #pragma unroll
    for (int i = 0; i < 4; ++i) {
        __half2 h[8];
        #pragma unroll
        for (int j = 0; j < 8; ++j)
            h[j] = __floats2half2_rn(Dm[i][j], ym[i][j]);
        __half2* dst = dbase + (v0 + i) * C_ + c0;
        *(uint4*)dst = *(const uint4*)&h[0];
        *(uint4*)(dst + 4) = *(const uint4*)&h[4];
    }
}

__global__ __launch_bounds__(256) void dkvmn_fused(
    const void* q_emb, const void* i_emb,
    const void* erase_b, const void* add_b,
    const int* __restrict__ input, const unsigned short* __restrict__ wpack,
    __half2* __restrict__ du)
{
    __shared__ FusedLDS sm;
    if (probe_flag_wave(erase_b))
        fused_body<true>(q_emb, i_emb, erase_b, add_b, input, wpack, du, sm);
    else
        fused_body<false>(q_emb, i_emb, erase_b, add_b, input, wpack, du, sm);
}

// ====== FoldFinal: 128 blocks (one per b) x 256 thr ======
// Folds the 4 (D,U) chunk slices (L2-resident: 2.1 MB/XCD, block b on XCD
// b%8 same as its writers), applies the wt read (readl in LDS), then the
// summ/out matvec straight to d_out. Kernel boundary is the sync point.
template<bool BF>
__device__ __forceinline__ void foldfinal_body(
    const void* init_value_memory, const void* q_emb,
    const void* summ_W, const void* summ_b,
    const void* out_W, const void* out_b,
    const int* __restrict__ target_id,
    const __half2* __restrict__ du, const float* __restrict__ wt_buf,
    void* __restrict__ outp, float* readl, float* summl)
{
    const int b = blockIdx.x;
    const int t = threadIdx.x;        // 0..255
    const int cg = t & 7;
    const int c0 = cg * 8;            // 8 c's = 8 half2 = 32 B per chunk

    float wt8[8];
    *(float4*)&wt8[0] = *(const float4*)(wt_buf + b * C_ + c0);
    *(float4*)&wt8[4] = *(const float4*)(wt_buf + b * C_ + c0 + 4);

    #pragma unroll
    for (int sub = 0; sub < 4; ++sub) {
        const int v = sub * 32 + (t >> 3);

        // issue all 8 independent 16-B loads together (vmcnt-pipelined)
        uint4 qa[NCH], qb[NCH];
        #pragma unroll
        for (int ch = 0; ch < NCH; ++ch) {
            const __half2* base = du + ((size_t)(ch * B_ + b) * (V_ * C_)) + v * C_ + c0;
            qa[ch] = *(const uint4*)base;         // c0..c0+3
            qb[ch] = *(const uint4*)(base + 4);   // c0+4..c0+7
        }

        float mem[8];
        #pragma unroll
        for (int k = 0; k < 8; ++k)
            mem[k] = ld<BF>(init_value_memory, v * C_ + c0 + k);

        #pragma unroll
        for (int ch = 0; ch < NCH; ++ch) {
            const __half2* hA = (const __half2*)&qa[ch];
            const __half2* hB = (const __half2*)&qb[ch];
            #pragma unroll
            for (int k = 0; k < 4; ++k) {
                const float2 fA = __half22float2(hA[k]);   // (D, U) for c0+k
                mem[k] = fmaf(fA.x, mem[k], fA.y);
                const float2 fB = __half22float2(hB[k]);   // (D, U) for c0+4+k
                mem[4 + k] = fmaf(fB.x, mem[4 + k], fB.y);
            }
        }

        float pacc = 0.f;
        #pragma unroll
        for (int k = 0; k < 8; ++k) pacc += mem[k] * wt8[k];
        pacc += __shfl_xor(pacc, 1, 64);
        pacc += __shfl_xor(pacc, 2, 64);
        pacc += __shfl_xor(pacc, 4, 64);
        if (cg == 0) readl[v] = pacc;
    }
    __syncthreads();

    if (t < SUM_) {
        const long long qrow = (long long)target_id[b] * K_;
        float acc = ld<BF>(summ_b, t);
        #pragma unroll 8
        for (int i = 0; i < 128; ++i)
            acc += readl[i] * ld<BF>(summ_W, i * SUM_ + t);
        #pragma unroll 8
        for (int i = 0; i < 128; ++i)
            acc += ld<BF>(q_emb, qrow + i) * ld<BF>(summ_W, (128 + i) * SUM_ + t);
        summl[t] = fast_tanh(acc);
    }
    __syncthreads();

    if (t < 64) {
        float oacc = summl[t] * ld<BF>(out_W, t) + summl[t + 64] * ld<BF>(out_W, t + 64);
        for (int off = 32; off > 0; off >>= 1)
            oacc += __shfl_xor(oacc, off, 64);
        if (t == 0) {
            const float res = oacc + ld<BF>(out_b, 0);
            if (BF) ((__hip_bfloat16*)outp)[b] = __float2bfloat16(res);
            else    ((float*)outp)[b] = res;
        }
    }
}

__global__ __launch_bounds__(256) void dkvmn_foldfinal(
    const void* init_value_memory, const void* q_emb,
    const void* summ_W, const void* summ_b,
    const void* out_W, const void* out_b, const void* erase_b,
    const int* __restrict__ target_id,
    const __half2* __restrict__ du, const float* __restrict__ wt_buf,
    void* __restrict__ outp)
{
    __shared__ float readl[V_], summl[SUM_];
    if (probe_flag_wave(erase_b))
        foldfinal_body<true>(init_value_memory, q_emb, summ_W, summ_b, out_W, out_b,
                             target_id, du, wt_buf, outp, readl, summl);
    else
        foldfinal_body<false>(init_value_memory, q_emb, summ_W, summ_b, out_W, out_b,
                              target_id, du, wt_buf, outp, readl, summl);
}

extern "C" void kernel_launch(void* const* d_in, const int* in_sizes, int n_in,
                              void* d_out, int out_size, void* d_ws, size_t ws_size,
                              hipStream_t stream) {
    const void* q_emb             = d_in[0];
    const void* i_emb             = d_in[1];
    const void* key_memory        = d_in[2];
    const void* init_value_memory = d_in[3];
    const void* erase_W           = d_in[4];
    const void* erase_b           = d_in[5];
    const void* add_W             = d_in[6];
    const void* add_b             = d_in[7];
    const void* summ_W            = d_in[8];
    const void* summ_b            = d_in[9];
    const void* out_W             = d_in[10];
    const void* out_b             = d_in[11];
    const int* input     = (const int*)d_in[12];
    const int* target_id = (const int*)d_in[13];

    // ws: wpack 80KB | du 16.8MB | wt_buf 32KB
    unsigned short* wpack = (unsigned short*)d_ws;
    __half2* du = (__half2*)(wpack + 5120 * 8);
    float* wt_buf = (float*)(du + (size_t)NCH * B_ * V_ * C_);

    dkvmn_prepack<<<148, 256, 0, stream>>>(
        erase_W, add_W, key_memory, erase_b, q_emb, target_id, wpack, wt_buf);
    dkvmn_fused<<<NCH * B_, 256, 0, stream>>>(
        q_emb, i_emb, erase_b, add_b, input, wpack, du);
    dkvmn_foldfinal<<<B_, 256, 0, stream>>>(
        init_value_memory, q_emb, summ_W, summ_b, out_W, out_b, erase_b,
        target_id, du, wt_buf, d_out);
}

// Round 7
// 143.129 us; speedup vs baseline: 1.0187x; 1.0187x over previous
//
#include <hip/hip_runtime.h>
#include <hip/hip_bf16.h>
#include <hip/hip_fp16.h>

#define B_ 128
#define S_ 200
#define QN_ 20000
#define V_ 128
#define K_ 128
#define C_ 64
#define SUM_ 128
#define NCH 4           // scan chunks (S = 4 * 50)
#define CL 50           // steps per chunk
#define RP 52           // padded row count in LDS

using short8 = __attribute__((ext_vector_type(8))) short;
using f32x4  = __attribute__((ext_vector_type(4))) float;

__device__ __forceinline__ float fast_sigmoid(float x) { return 1.f / (1.f + __expf(-x)); }
__device__ __forceinline__ float fast_tanh(float x)    { return 1.f - 2.f / (__expf(2.f * x) + 1.f); }

template<bool BF>
__device__ __forceinline__ float ld(const void* p, long long i) {
    if (BF) return __bfloat162float(((const __hip_bfloat16*)p)[i]);
    return ((const float*)p)[i];
}

__device__ __forceinline__ unsigned short f2bf(float v) {
    __hip_bfloat16 h = __float2bfloat16(v);
    unsigned short u;
    __builtin_memcpy(&u, &h, 2);
    return u;
}

__device__ __forceinline__ void ld4h(const __half* p, float* out) {
    const float2 f01 = __half22float2(*(const __half2*)p);
    const float2 f23 = __half22float2(*(const __half2*)(p + 2));
    out[0] = f01.x; out[1] = f01.y; out[2] = f23.x; out[3] = f23.y;
}

__device__ __forceinline__ int probe_flag_wave(const void* erase_b) {
    const unsigned* w = (const unsigned*)erase_b;
    const int lane = threadIdx.x & 63;
    const unsigned lo = w[lane] & 0xffffu;
    const float f = __uint_as_float(lo << 16);
    const unsigned long long bal = __ballot(!(fabsf(f) <= 0.5f));
    return (__popcll(bal) <= 8) ? 1 : 0;  // 1 = bf16
}

// ============ Fused phase1+scan: 512 blocks (b, chunk), 256 threads ============
// Self-contained: each block packs its own W fragments (same index math and
// f2bf rounding as the old prepack — weights are 160 KB, L2-hot) so no
// producer kernel is needed.
struct FusedLDS {
    unsigned short ivA[RP * 136];
    unsigned short qvA[RP * 136];
    __half esh[RP * 136];
    __half ash[RP * 136];
    float  wlog[RP * 68];
    int sidx[RP], sqid[RP];
};

template<bool BF>
__device__ __forceinline__ void fused_body(
    const void* q_emb, const void* i_emb,
    const void* erase_W, const void* add_W, const void* key_memory,
    const void* erase_b, const void* add_b,
    const int* __restrict__ input,
    __half2* __restrict__ du, FusedLDS& sm)
{
    const int bid = blockIdx.x;
    const int b = bid & 127;            // XCD affinity: all chunks of b on b%8
    const int chunk = bid >> 7;         // 0..3
    const int t = threadIdx.x;          // 0..255
    const int wv = t >> 6;
    const int lane = t & 63;
    const int lrow = lane & 15;
    const int lk8 = (lane >> 4) * 8;

    if (t < RP) {
        const int s = (t < CL) ? t : 0;
        const int ix = input[b * S_ + chunk * CL + s];
        sm.sidx[t] = ix;
        sm.sqid[t] = ix > QN_ ? ix - QN_ : ix;
    }
    __syncthreads();

    // stage 2 tensors x RP rows x 16 segs of 8 elements = 1664 jobs
    #pragma unroll
    for (int r = 0; r < 7; ++r) {
        const int j = t + 256 * r;      // 0..1791
        if (j < 2 * RP * 16) {
            const int tensor = j >= RP * 16;
            const int jj = j - tensor * (RP * 16);
            const int row = jj >> 4;
            const int seg = jj & 15;
            const int gr = tensor ? sm.sqid[row] : sm.sidx[row];
            unsigned short* dst = (tensor ? sm.qvA : sm.ivA) + row * 136 + seg * 8;
            if (BF) {
                const unsigned short* src = (const unsigned short*)(tensor ? q_emb : i_emb);
                *(uint4*)dst = *(const uint4*)(src + (long long)gr * 128 + seg * 8);
            } else {
                const float* src = (const float*)(tensor ? q_emb : i_emb) + (long long)gr * 128 + seg * 8;
                const float4 f0 = *(const float4*)src;
                const float4 f1 = *(const float4*)(src + 4);
                unsigned short o[8] = {f2bf(f0.x), f2bf(f0.y), f2bf(f0.z), f2bf(f0.w),
                                       f2bf(f1.x), f2bf(f1.y), f2bf(f1.z), f2bf(f1.w)};
                *(uint4*)dst = *(const uint4*)o;
            }
        }
    }

    // pack W fragments in-register (exactly the old prepack math: same idx,
    // same f2bf rounding). 160 scalar loads/thread, all L2-hot.
    short8 bfr[5][4];
    int nco[5];
    float biasq[4];
    #pragma unroll
    for (int q = 0; q < 5; ++q) {
        const int nt = wv + 4 * q;
        const void* Wsrc;
        int ldn;
        if (q < 2)      { Wsrc = erase_W;    nco[q] = nt * 16 + lrow;        ldn = 128; }
        else if (q < 4) { Wsrc = add_W;      nco[q] = (nt - 8) * 16 + lrow;  ldn = 128; }
        else            { Wsrc = key_memory; nco[q] = (nt - 16) * 16 + lrow; ldn = 64; }
        if (q < 2)      biasq[q] = ld<BF>(erase_b, nco[q]);
        else if (q < 4) biasq[q] = ld<BF>(add_b, nco[q]);
        #pragma unroll
        for (int ks = 0; ks < 4; ++ks) {
            unsigned short o[8];
            #pragma unroll
            for (int jj = 0; jj < 8; ++jj) {
                const long long idx = (long long)(ks * 32 + lk8 + jj) * ldn + nco[q];
                o[jj] = f2bf(ld<BF>(Wsrc, idx));
            }
            bfr[q][ks] = *(const short8*)o;
        }
    }
    __syncthreads();

    // e/a: 4 m-tiles cover rows 0..63; stores guarded to rows < CL
    #pragma unroll
    for (int mt = 0; mt < 4; ++mt) {
        short8 afr[4];
        const unsigned short* ar = sm.ivA + (mt * 16 + lrow) * 136 + lk8;
        #pragma unroll
        for (int ks = 0; ks < 4; ++ks)
            afr[ks] = *(const short8*)(ar + ks * 32);
        #pragma unroll
        for (int q = 0; q < 4; ++q) {
            f32x4 acc = {0.f, 0.f, 0.f, 0.f};
            #pragma unroll
            for (int ks = 0; ks < 4; ++ks)
                acc = __builtin_amdgcn_mfma_f32_16x16x32_bf16(afr[ks], bfr[q][ks], acc, 0, 0, 0);
            const int ncol = nco[q];
            const float bb = biasq[q];
            #pragma unroll
            for (int r = 0; r < 4; ++r) {
                const int orow = mt * 16 + (lane >> 4) * 4 + r;
                if (orow < CL) {
                    const float y = acc[r] + bb;
                    if (q < 2) sm.esh[orow * 136 + ncol] = __float2half(fast_sigmoid(y));
                    else       sm.ash[orow * 136 + ncol] = __float2half(fast_tanh(y));
                }
            }
        }
    }
    // w logits
    #pragma unroll
    for (int mt = 0; mt < 4; ++mt) {
        short8 afr[4];
        const unsigned short* ar = sm.qvA + (mt * 16 + lrow) * 136 + lk8;
        #pragma unroll
        for (int ks = 0; ks < 4; ++ks)
            afr[ks] = *(const short8*)(ar + ks * 32);
        f32x4 acc = {0.f, 0.f, 0.f, 0.f};
        #pragma unroll
        for (int ks = 0; ks < 4; ++ks)
            acc = __builtin_amdgcn_mfma_f32_16x16x32_bf16(afr[ks], bfr[4][ks], acc, 0, 0, 0);
        #pragma unroll
        for (int r = 0; r < 4; ++r) {
            const int orow = mt * 16 + (lane >> 4) * 4 + r;
            if (orow < CL)
                sm.wlog[orow * 68 + nco[4]] = acc[r];
        }
    }
    __syncthreads();

    // softmax over c=64 per row; 2 passes of 32 rows; aligned 8-thread groups
    #pragma unroll
    for (int pass = 0; pass < 2; ++pass) {
        const int row = pass * 32 + (t >> 3);
        if (row < CL) {
            const int cs = t & 7;
            float* wr = &sm.wlog[row * 68 + cs * 8];
            float v[8];
            *(float4*)&v[0] = *(const float4*)&wr[0];
            *(float4*)&v[4] = *(const float4*)&wr[4];
            float m = v[0];
            #pragma unroll
            for (int ii = 1; ii < 8; ++ii) m = fmaxf(m, v[ii]);
            m = fmaxf(m, __shfl_xor(m, 1, 64));
            m = fmaxf(m, __shfl_xor(m, 2, 64));
            m = fmaxf(m, __shfl_xor(m, 4, 64));
            float s = 0.f;
            #pragma unroll
            for (int ii = 0; ii < 8; ++ii) { v[ii] = __expf(v[ii] - m); s += v[ii]; }
            s += __shfl_xor(s, 1, 64);
            s += __shfl_xor(s, 2, 64);
            s += __shfl_xor(s, 4, 64);
            const float inv = 1.f / s;
            *(float4*)&wr[0] = make_float4(v[0]*inv, v[1]*inv, v[2]*inv, v[3]*inv);
            *(float4*)&wr[4] = make_float4(v[4]*inv, v[5]*inv, v[6]*inv, v[7]*inv);
        }
    }
    __syncthreads();

    const int vg = t >> 3;
    const int cg = t & 7;
    const int v0 = vg * 4, c0 = cg * 8;

    float ym[4][8], Dm[4][8];
    #pragma unroll
    for (int i = 0; i < 4; ++i)
        #pragma unroll
        for (int j = 0; j < 8; ++j) { ym[i][j] = 0.f; Dm[i][j] = 1.f; }

    for (int s = 0; s < CL; ++s) {
        float ev[4], av[4], wv8[8];
        ld4h(sm.esh + s * 136 + v0, ev);
        ld4h(sm.ash + s * 136 + v0, av);
        *(float4*)&wv8[0] = *(const float4*)(sm.wlog + s * 68 + c0);
        *(float4*)&wv8[4] = *(const float4*)(sm.wlog + s * 68 + c0 + 4);
        #pragma unroll
        for (int i = 0; i < 4; ++i) {
            #pragma unroll
            for (int j = 0; j < 8; ++j) {
                const float d = fmaf(-ev[i], wv8[j], 1.f);
                Dm[i][j] *= d;
                ym[i][j] = fmaf(d, ym[i][j], av[i] * wv8[j]);
            }
        }
    }

    __half2* dbase = du + ((size_t)(chunk * B_ + b) * (V_ * C_));
    #pragma unroll
    for (int i = 0; i < 4; ++i) {
        __half2 h[8];
        #pragma unroll
        for (int j = 0; j < 8; ++j)
            h[j] = __floats2half2_rn(Dm[i][j], ym[i][j]);
        __half2* dst = dbase + (v0 + i) * C_ + c0;
        *(uint4*)dst = *(const uint4*)&h[0];
        *(uint4*)(dst + 4) = *(const uint4*)&h[4];
    }
}

__global__ __launch_bounds__(256) void dkvmn_fused(
    const void* q_emb, const void* i_emb,
    const void* erase_W, const void* add_W, const void* key_memory,
    const void* erase_b, const void* add_b,
    const int* __restrict__ input,
    __half2* __restrict__ du)
{
    __shared__ FusedLDS sm;
    if (probe_flag_wave(erase_b))
        fused_body<true>(q_emb, i_emb, erase_W, add_W, key_memory,
                         erase_b, add_b, input, du, sm);
    else
        fused_body<false>(q_emb, i_emb, erase_W, add_W, key_memory,
                          erase_b, add_b, input, du, sm);
}

// ====== FoldFinal: 128 blocks (one per b) x 256 thr ======
// Wave 0 computes the target softmax wt (identical math to the old wt_body)
// into LDS; then all threads fold the 4 (D,U) chunk slices (L2-resident,
// XCD-local), apply the wt read, and run the summ/out matvec to d_out.
template<bool BF>
__device__ __forceinline__ void foldfinal_body(
    const void* init_value_memory, const void* q_emb, const void* key_memory,
    const void* summ_W, const void* summ_b,
    const void* out_W, const void* out_b,
    const int* __restrict__ target_id,
    const __half2* __restrict__ du,
    void* __restrict__ outp, float* wtl, float* readl, float* summl)
{
    const int b = blockIdx.x;
    const int t = threadIdx.x;        // 0..255
    const int cg = t & 7;
    const int c0 = cg * 8;            // 8 c's = 8 half2 = 32 B per chunk

    if (t < 64) {                     // wave 0: wt softmax (same math as old wt_body)
        const long long qrow = (long long)target_id[b] * K_;
        float logit = 0.f;
        #pragma unroll 8
        for (int i = 0; i < K_; ++i)
            logit += ld<BF>(q_emb, qrow + i) * ld<BF>(key_memory, i * C_ + t);
        float m = logit;
        for (int off = 32; off > 0; off >>= 1)
            m = fmaxf(m, __shfl_xor(m, off, 64));
        const float ex = __expf(logit - m);
        float ssum = ex;
        for (int off = 32; off > 0; off >>= 1)
            ssum += __shfl_xor(ssum, off, 64);
        wtl[t] = ex / ssum;
    }
    __syncthreads();

    float wt8[8];
    *(float4*)&wt8[0] = *(const float4*)(wtl + c0);
    *(float4*)&wt8[4] = *(const float4*)(wtl + c0 + 4);

    #pragma unroll
    for (int sub = 0; sub < 4; ++sub) {
        const int v = sub * 32 + (t >> 3);

        uint4 qa[NCH], qb[NCH];
        #pragma unroll
        for (int ch = 0; ch < NCH; ++ch) {
            const __half2* base = du + ((size_t)(ch * B_ + b) * (V_ * C_)) + v * C_ + c0;
            qa[ch] = *(const uint4*)base;         // c0..c0+3
            qb[ch] = *(const uint4*)(base + 4);   // c0+4..c0+7
        }

        float mem[8];
        #pragma unroll
        for (int k = 0; k < 8; ++k)
            mem[k] = ld<BF>(init_value_memory, v * C_ + c0 + k);

        #pragma unroll
        for (int ch = 0; ch < NCH; ++ch) {
            const __half2* hA = (const __half2*)&qa[ch];
            const __half2* hB = (const __half2*)&qb[ch];
            #pragma unroll
            for (int k = 0; k < 4; ++k) {
                const float2 fA = __half22float2(hA[k]);   // (D, U) for c0+k
                mem[k] = fmaf(fA.x, mem[k], fA.y);
                const float2 fB = __half22float2(hB[k]);   // (D, U) for c0+4+k
                mem[4 + k] = fmaf(fB.x, mem[4 + k], fB.y);
            }
        }

        float pacc = 0.f;
        #pragma unroll
        for (int k = 0; k < 8; ++k) pacc += mem[k] * wt8[k];
        pacc += __shfl_xor(pacc, 1, 64);
        pacc += __shfl_xor(pacc, 2, 64);
        pacc += __shfl_xor(pacc, 4, 64);
        if (cg == 0) readl[v] = pacc;
    }
    __syncthreads();

    if (t < SUM_) {
        const long long qrow = (long long)target_id[b] * K_;
        float acc = ld<BF>(summ_b, t);
        #pragma unroll 8
        for (int i = 0; i < 128; ++i)
            acc += readl[i] * ld<BF>(summ_W, i * SUM_ + t);
        #pragma unroll 8
        for (int i = 0; i < 128; ++i)
            acc += ld<BF>(q_emb, qrow + i) * ld<BF>(summ_W, (128 + i) * SUM_ + t);
        summl[t] = fast_tanh(acc);
    }
    __syncthreads();

    if (t < 64) {
        float oacc = summl[t] * ld<BF>(out_W, t) + summl[t + 64] * ld<BF>(out_W, t + 64);
        for (int off = 32; off > 0; off >>= 1)
            oacc += __shfl_xor(oacc, off, 64);
        if (t == 0) {
            const float res = oacc + ld<BF>(out_b, 0);
            if (BF) ((__hip_bfloat16*)outp)[b] = __float2bfloat16(res);
            else    ((float*)outp)[b] = res;
        }
    }
}

__global__ __launch_bounds__(256) void dkvmn_foldfinal(
    const void* init_value_memory, const void* q_emb, const void* key_memory,
    const void* summ_W, const void* summ_b,
    const void* out_W, const void* out_b, const void* erase_b,
    const int* __restrict__ target_id,
    const __half2* __restrict__ du,
    void* __restrict__ outp)
{
    __shared__ float wtl[C_], readl[V_], summl[SUM_];
    if (probe_flag_wave(erase_b))
        foldfinal_body<true>(init_value_memory, q_emb, key_memory, summ_W, summ_b,
                             out_W, out_b, target_id, du, outp, wtl, readl, summl);
    else
        foldfinal_body<false>(init_value_memory, q_emb, key_memory, summ_W, summ_b,
                              out_W, out_b, target_id, du, outp, wtl, readl, summl);
}

extern "C" void kernel_launch(void* const* d_in, const int* in_sizes, int n_in,
                              void* d_out, int out_size, void* d_ws, size_t ws_size,
                              hipStream_t stream) {
    const void* q_emb             = d_in[0];
    const void* i_emb             = d_in[1];
    const void* key_memory        = d_in[2];
    const void* init_value_memory = d_in[3];
    const void* erase_W           = d_in[4];
    const void* erase_b           = d_in[5];
    const void* add_W             = d_in[6];
    const void* add_b             = d_in[7];
    const void* summ_W            = d_in[8];
    const void* summ_b            = d_in[9];
    const void* out_W             = d_in[10];
    const void* out_b             = d_in[11];
    const int* input     = (const int*)d_in[12];
    const int* target_id = (const int*)d_in[13];

    // ws: du 16.8MB
    __half2* du = (__half2*)d_ws;

    dkvmn_fused<<<NCH * B_, 256, 0, stream>>>(
        q_emb, i_emb, erase_W, add_W, key_memory, erase_b, add_b, input, du);
    dkvmn_foldfinal<<<B_, 256, 0, stream>>>(
        init_value_memory, q_emb, key_memory, summ_W, summ_b, out_W, out_b,
        erase_b, target_id, du, d_out);
}

// Round 8
// 140.942 us; speedup vs baseline: 1.0345x; 1.0155x over previous
//
#include <hip/hip_runtime.h>
#include <hip/hip_bf16.h>
#include <hip/hip_fp16.h>

#define B_ 128
#define S_ 200
#define QN_ 20000
#define V_ 128
#define K_ 128
#define C_ 64
#define SUM_ 128
#define NCH 4           // scan chunks (S = 4 * 50)
#define CL 50           // steps per chunk
#define RP 52           // padded row count in LDS

using short8 = __attribute__((ext_vector_type(8))) short;
using f32x4  = __attribute__((ext_vector_type(4))) float;

__device__ __forceinline__ float fast_sigmoid(float x) { return 1.f / (1.f + __expf(-x)); }
__device__ __forceinline__ float fast_tanh(float x)    { return 1.f - 2.f / (__expf(2.f * x) + 1.f); }

template<bool BF>
__device__ __forceinline__ float ld(const void* p, long long i) {
    if (BF) return __bfloat162float(((const __hip_bfloat16*)p)[i]);
    return ((const float*)p)[i];
}

__device__ __forceinline__ unsigned short f2bf(float v) {
    __hip_bfloat16 h = __float2bfloat16(v);
    unsigned short u;
    __builtin_memcpy(&u, &h, 2);
    return u;
}

__device__ __forceinline__ int probe_flag_wave(const void* erase_b) {
    const unsigned* w = (const unsigned*)erase_b;
    const int lane = threadIdx.x & 63;
    const unsigned lo = w[lane] & 0xffffu;
    const float f = __uint_as_float(lo << 16);
    const unsigned long long bal = __ballot(!(fabsf(f) <= 0.5f));
    return (__popcll(bal) <= 8) ? 1 : 0;  // 1 = bf16
}

// ============ Fused phase1+scan: 512 blocks (b, chunk), 256 threads ============
// Self-contained: each block packs its own W fragments (same index math and
// f2bf rounding as the old prepack — weights are 160 KB, L2-hot).
// Scan runs in packed fp16 (v_pk_fma_f16 via __hfma2): 2 elems/lane-op.
struct FusedLDS {
    unsigned short ivA[RP * 136];
    unsigned short qvA[RP * 136];
    __half esh[RP * 136];
    __half ash[RP * 136];
    float  wlog[RP * 68];
    int sidx[RP], sqid[RP];
};

template<bool BF>
__device__ __forceinline__ void fused_body(
    const void* q_emb, const void* i_emb,
    const void* erase_W, const void* add_W, const void* key_memory,
    const void* erase_b, const void* add_b,
    const int* __restrict__ input,
    __half* __restrict__ du, FusedLDS& sm)
{
    const int bid = blockIdx.x;
    const int b = bid & 127;            // XCD affinity: all chunks of b on b%8
    const int chunk = bid >> 7;         // 0..3
    const int t = threadIdx.x;          // 0..255
    const int wv = t >> 6;
    const int lane = t & 63;
    const int lrow = lane & 15;
    const int lk8 = (lane >> 4) * 8;

    if (t < RP) {
        const int s = (t < CL) ? t : 0;
        const int ix = input[b * S_ + chunk * CL + s];
        sm.sidx[t] = ix;
        sm.sqid[t] = ix > QN_ ? ix - QN_ : ix;
    }
    __syncthreads();

    // stage 2 tensors x RP rows x 16 segs of 8 elements = 1664 jobs
    #pragma unroll
    for (int r = 0; r < 7; ++r) {
        const int j = t + 256 * r;      // 0..1791
        if (j < 2 * RP * 16) {
            const int tensor = j >= RP * 16;
            const int jj = j - tensor * (RP * 16);
            const int row = jj >> 4;
            const int seg = jj & 15;
            const int gr = tensor ? sm.sqid[row] : sm.sidx[row];
            unsigned short* dst = (tensor ? sm.qvA : sm.ivA) + row * 136 + seg * 8;
            if (BF) {
                const unsigned short* src = (const unsigned short*)(tensor ? q_emb : i_emb);
                *(uint4*)dst = *(const uint4*)(src + (long long)gr * 128 + seg * 8);
            } else {
                const float* src = (const float*)(tensor ? q_emb : i_emb) + (long long)gr * 128 + seg * 8;
                const float4 f0 = *(const float4*)src;
                const float4 f1 = *(const float4*)(src + 4);
                unsigned short o[8] = {f2bf(f0.x), f2bf(f0.y), f2bf(f0.z), f2bf(f0.w),
                                       f2bf(f1.x), f2bf(f1.y), f2bf(f1.z), f2bf(f1.w)};
                *(uint4*)dst = *(const uint4*)o;
            }
        }
    }

    // pack W fragments in-register (exactly the old prepack math: same idx,
    // same f2bf rounding). 160 scalar loads/thread, all L2-hot.
    short8 bfr[5][4];
    int nco[5];
    float biasq[4];
    #pragma unroll
    for (int q = 0; q < 5; ++q) {
        const int nt = wv + 4 * q;
        const void* Wsrc;
        int ldn;
        if (q < 2)      { Wsrc = erase_W;    nco[q] = nt * 16 + lrow;        ldn = 128; }
        else if (q < 4) { Wsrc = add_W;      nco[q] = (nt - 8) * 16 + lrow;  ldn = 128; }
        else            { Wsrc = key_memory; nco[q] = (nt - 16) * 16 + lrow; ldn = 64; }
        if (q < 2)      biasq[q] = ld<BF>(erase_b, nco[q]);
        else if (q < 4) biasq[q] = ld<BF>(add_b, nco[q]);
        #pragma unroll
        for (int ks = 0; ks < 4; ++ks) {
            unsigned short o[8];
            #pragma unroll
            for (int jj = 0; jj < 8; ++jj) {
                const long long idx = (long long)(ks * 32 + lk8 + jj) * ldn + nco[q];
                o[jj] = f2bf(ld<BF>(Wsrc, idx));
            }
            bfr[q][ks] = *(const short8*)o;
        }
    }
    __syncthreads();

    // e/a: 4 m-tiles cover rows 0..63; stores guarded to rows < CL
    #pragma unroll
    for (int mt = 0; mt < 4; ++mt) {
        short8 afr[4];
        const unsigned short* ar = sm.ivA + (mt * 16 + lrow) * 136 + lk8;
        #pragma unroll
        for (int ks = 0; ks < 4; ++ks)
            afr[ks] = *(const short8*)(ar + ks * 32);
        #pragma unroll
        for (int q = 0; q < 4; ++q) {
            f32x4 acc = {0.f, 0.f, 0.f, 0.f};
            #pragma unroll
            for (int ks = 0; ks < 4; ++ks)
                acc = __builtin_amdgcn_mfma_f32_16x16x32_bf16(afr[ks], bfr[q][ks], acc, 0, 0, 0);
            const int ncol = nco[q];
            const float bb = biasq[q];
            #pragma unroll
            for (int r = 0; r < 4; ++r) {
                const int orow = mt * 16 + (lane >> 4) * 4 + r;
                if (orow < CL) {
                    const float y = acc[r] + bb;
                    if (q < 2) sm.esh[orow * 136 + ncol] = __float2half(fast_sigmoid(y));
                    else       sm.ash[orow * 136 + ncol] = __float2half(fast_tanh(y));
                }
            }
        }
    }
    // w logits
    #pragma unroll
    for (int mt = 0; mt < 4; ++mt) {
        short8 afr[4];
        const unsigned short* ar = sm.qvA + (mt * 16 + lrow) * 136 + lk8;
        #pragma unroll
        for (int ks = 0; ks < 4; ++ks)
            afr[ks] = *(const short8*)(ar + ks * 32);
        f32x4 acc = {0.f, 0.f, 0.f, 0.f};
        #pragma unroll
        for (int ks = 0; ks < 4; ++ks)
            acc = __builtin_amdgcn_mfma_f32_16x16x32_bf16(afr[ks], bfr[4][ks], acc, 0, 0, 0);
        #pragma unroll
        for (int r = 0; r < 4; ++r) {
            const int orow = mt * 16 + (lane >> 4) * 4 + r;
            if (orow < CL)
                sm.wlog[orow * 68 + nco[4]] = acc[r];
        }
    }
    __syncthreads();

    // softmax over c=64 per row; 2 passes of 32 rows; aligned 8-thread groups
    #pragma unroll
    for (int pass = 0; pass < 2; ++pass) {
        const int row = pass * 32 + (t >> 3);
        if (row < CL) {
            const int cs = t & 7;
            float* wr = &sm.wlog[row * 68 + cs * 8];
            float v[8];
            *(float4*)&v[0] = *(const float4*)&wr[0];
            *(float4*)&v[4] = *(const float4*)&wr[4];
            float m = v[0];
            #pragma unroll
            for (int ii = 1; ii < 8; ++ii) m = fmaxf(m, v[ii]);
            m = fmaxf(m, __shfl_xor(m, 1, 64));
            m = fmaxf(m, __shfl_xor(m, 2, 64));
            m = fmaxf(m, __shfl_xor(m, 4, 64));
            float s = 0.f;
            #pragma unroll
            for (int ii = 0; ii < 8; ++ii) { v[ii] = __expf(v[ii] - m); s += v[ii]; }
            s += __shfl_xor(s, 1, 64);
            s += __shfl_xor(s, 2, 64);
            s += __shfl_xor(s, 4, 64);
            const float inv = 1.f / s;
            *(float4*)&wr[0] = make_float4(v[0]*inv, v[1]*inv, v[2]*inv, v[3]*inv);
            *(float4*)&wr[4] = make_float4(v[4]*inv, v[5]*inv, v[6]*inv, v[7]*inv);
        }
    }
    __syncthreads();

    const int vg = t >> 3;
    const int cg = t & 7;
    const int v0 = vg * 4, c0 = cg * 8;

    // ---- packed-fp16 scan: state (D,U) as half2 pairs along c ----
    const __half2 one2 = __floats2half2_rn(1.f, 1.f);
    const __half2 zero2 = __floats2half2_rn(0.f, 0.f);
    __half2 Dm2[4][4], Um2[4][4];
    #pragma unroll
    for (int i = 0; i < 4; ++i)
        #pragma unroll
        for (int jp = 0; jp < 4; ++jp) { Dm2[i][jp] = one2; Um2[i][jp] = zero2; }

    for (int s = 0; s < CL; ++s) {
        const __half2 e01 = *(const __half2*)(sm.esh + s * 136 + v0);
        const __half2 e23 = *(const __half2*)(sm.esh + s * 136 + v0 + 2);
        const __half2 a01 = *(const __half2*)(sm.ash + s * 136 + v0);
        const __half2 a23 = *(const __half2*)(sm.ash + s * 136 + v0 + 2);
        const float4 wf0 = *(const float4*)(sm.wlog + s * 68 + c0);
        const float4 wf1 = *(const float4*)(sm.wlog + s * 68 + c0 + 4);
        const __half2 w2[4] = { __floats2half2_rn(wf0.x, wf0.y), __floats2half2_rn(wf0.z, wf0.w),
                                __floats2half2_rn(wf1.x, wf1.y), __floats2half2_rn(wf1.z, wf1.w) };
        const __half2 e2[4] = { __low2half2(e01), __high2half2(e01),
                                __low2half2(e23), __high2half2(e23) };
        const __half2 a2[4] = { __low2half2(a01), __high2half2(a01),
                                __low2half2(a23), __high2half2(a23) };
        #pragma unroll
        for (int i = 0; i < 4; ++i) {
            const __half2 ne = __hneg2(e2[i]);
            #pragma unroll
            for (int jp = 0; jp < 4; ++jp) {
                const __half2 d2 = __hfma2(ne, w2[jp], one2);
                Dm2[i][jp] = __hmul2(Dm2[i][jp], d2);
                Um2[i][jp] = __hfma2(d2, Um2[i][jp], __hmul2(a2[i], w2[jp]));
            }
        }
    }

    // du planar layout per (chunk,b,v): 64 D halves then 64 U halves (256 B/row)
    __half* dbase = du + ((size_t)(chunk * B_ + b) * (V_ * C_ * 2));
    #pragma unroll
    for (int i = 0; i < 4; ++i) {
        __half* dst = dbase + (size_t)(v0 + i) * (C_ * 2) + c0;
        *(uint4*)dst        = *(const uint4*)&Dm2[i][0];   // D[c0..c0+7]
        *(uint4*)(dst + C_) = *(const uint4*)&Um2[i][0];   // U[c0..c0+7]
    }
}

__global__ __launch_bounds__(256) void dkvmn_fused(
    const void* q_emb, const void* i_emb,
    const void* erase_W, const void* add_W, const void* key_memory,
    const void* erase_b, const void* add_b,
    const int* __restrict__ input,
    __half* __restrict__ du)
{
    __shared__ FusedLDS sm;
    if (probe_flag_wave(erase_b))
        fused_body<true>(q_emb, i_emb, erase_W, add_W, key_memory,
                         erase_b, add_b, input, du, sm);
    else
        fused_body<false>(q_emb, i_emb, erase_W, add_W, key_memory,
                          erase_b, add_b, input, du, sm);
}

// ====== FoldFinal: 128 blocks (one per b) x 256 thr ======
// Wave 0 computes the target softmax wt into LDS; then all threads fold the
// 4 (D,U) chunk slices (planar half layout; L2-resident, XCD-local), apply
// the wt read, and run the summ/out matvec to d_out.
template<bool BF>
__device__ __forceinline__ void foldfinal_body(
    const void* init_value_memory, const void* q_emb, const void* key_memory,
    const void* summ_W, const void* summ_b,
    const void* out_W, const void* out_b,
    const int* __restrict__ target_id,
    const __half* __restrict__ du,
    void* __restrict__ outp, float* wtl, float* readl, float* summl)
{
    const int b = blockIdx.x;
    const int t = threadIdx.x;        // 0..255
    const int cg = t & 7;
    const int c0 = cg * 8;            // 8 consecutive c's per thread

    if (t < 64) {                     // wave 0: wt softmax
        const long long qrow = (long long)target_id[b] * K_;
        float logit = 0.f;
        #pragma unroll 8
        for (int i = 0; i < K_; ++i)
            logit += ld<BF>(q_emb, qrow + i) * ld<BF>(key_memory, i * C_ + t);
        float m = logit;
        for (int off = 32; off > 0; off >>= 1)
            m = fmaxf(m, __shfl_xor(m, off, 64));
        const float ex = __expf(logit - m);
        float ssum = ex;
        for (int off = 32; off > 0; off >>= 1)
            ssum += __shfl_xor(ssum, off, 64);
        wtl[t] = ex / ssum;
    }
    __syncthreads();

    float wt8[8];
    *(float4*)&wt8[0] = *(const float4*)(wtl + c0);
    *(float4*)&wt8[4] = *(const float4*)(wtl + c0 + 4);

    #pragma unroll
    for (int sub = 0; sub < 4; ++sub) {
        const int v = sub * 32 + (t >> 3);

        uint4 qa[NCH], qb[NCH];      // D-pack / U-pack (8 halves each)
        #pragma unroll
        for (int ch = 0; ch < NCH; ++ch) {
            const __half* base = du + ((size_t)(ch * B_ + b) * (V_ * C_ * 2))
                                    + (size_t)v * (C_ * 2) + c0;
            qa[ch] = *(const uint4*)base;          // D[c0..c0+7]
            qb[ch] = *(const uint4*)(base + C_);   // U[c0..c0+7]
        }

        float mem[8];
        #pragma unroll
        for (int k = 0; k < 8; ++k)
            mem[k] = ld<BF>(init_value_memory, v * C_ + c0 + k);

        #pragma unroll
        for (int ch = 0; ch < NCH; ++ch) {
            const __half2* hD = (const __half2*)&qa[ch];
            const __half2* hU = (const __half2*)&qb[ch];
            #pragma unroll
            for (int k = 0; k < 4; ++k) {
                const float2 fD = __half22float2(hD[k]);
                const float2 fU = __half22float2(hU[k]);
                mem[2 * k]     = fmaf(fD.x, mem[2 * k],     fU.x);
                mem[2 * k + 1] = fmaf(fD.y, mem[2 * k + 1], fU.y);
            }
        }

        float pacc = 0.f;
        #pragma unroll
        for (int k = 0; k < 8; ++k) pacc += mem[k] * wt8[k];
        pacc += __shfl_xor(pacc, 1, 64);
        pacc += __shfl_xor(pacc, 2, 64);
        pacc += __shfl_xor(pacc, 4, 64);
        if (cg == 0) readl[v] = pacc;
    }
    __syncthreads();

    if (t < SUM_) {
        const long long qrow = (long long)target_id[b] * K_;
        float acc = ld<BF>(summ_b, t);
        #pragma unroll 8
        for (int i = 0; i < 128; ++i)
            acc += readl[i] * ld<BF>(summ_W, i * SUM_ + t);
        #pragma unroll 8
        for (int i = 0; i < 128; ++i)
            acc += ld<BF>(q_emb, qrow + i) * ld<BF>(summ_W, (128 + i) * SUM_ + t);
        summl[t] = fast_tanh(acc);
    }
    __syncthreads();

    if (t < 64) {
        float oacc = summl[t] * ld<BF>(out_W, t) + summl[t + 64] * ld<BF>(out_W, t + 64);
        for (int off = 32; off > 0; off >>= 1)
            oacc += __shfl_xor(oacc, off, 64);
        if (t == 0) {
            const float res = oacc + ld<BF>(out_b, 0);
            if (BF) ((__hip_bfloat16*)outp)[b] = __float2bfloat16(res);
            else    ((float*)outp)[b] = res;
        }
    }
}

__global__ __launch_bounds__(256) void dkvmn_foldfinal(
    const void* init_value_memory, const void* q_emb, const void* key_memory,
    const void* summ_W, const void* summ_b,
    const void* out_W, const void* out_b, const void* erase_b,
    const int* __restrict__ target_id,
    const __half* __restrict__ du,
    void* __restrict__ outp)
{
    __shared__ float wtl[C_], readl[V_], summl[SUM_];
    if (probe_flag_wave(erase_b))
        foldfinal_body<true>(init_value_memory, q_emb, key_memory, summ_W, summ_b,
                             out_W, out_b, target_id, du, outp, wtl, readl, summl);
    else
        foldfinal_body<false>(init_value_memory, q_emb, key_memory, summ_W, summ_b,
                              out_W, out_b, target_id, du, outp, wtl, readl, summl);
}

extern "C" void kernel_launch(void* const* d_in, const int* in_sizes, int n_in,
                              void* d_out, int out_size, void* d_ws, size_t ws_size,
                              hipStream_t stream) {
    const void* q_emb             = d_in[0];
    const void* i_emb             = d_in[1];
    const void* key_memory        = d_in[2];
    const void* init_value_memory = d_in[3];
    const void* erase_W           = d_in[4];
    const void* erase_b           = d_in[5];
    const void* add_W             = d_in[6];
    const void* add_b             = d_in[7];
    const void* summ_W            = d_in[8];
    const void* summ_b            = d_in[9];
    const void* out_W             = d_in[10];
    const void* out_b             = d_in[11];
    const int* input     = (const int*)d_in[12];
    const int* target_id = (const int*)d_in[13];

    // ws: du 16.8MB (planar D/U half planes)
    __half* du = (__half*)d_ws;

    dkvmn_fused<<<NCH * B_, 256, 0, stream>>>(
        q_emb, i_emb, erase_W, add_W, key_memory, erase_b, add_b, input, du);
    dkvmn_foldfinal<<<B_, 256, 0, stream>>>(
        init_value_memory, q_emb, key_memory, summ_W, summ_b, out_W, out_b,
        erase_b, target_id, du, d_out);
}